// Round 10
// baseline (95.291 us; speedup 1.0000x reference)
//
#include <hip/hip_runtime.h>
#include <hip/hip_bf16.h>
#include <math.h>

#define NN 512
#define HH 128
#define FF 32
#define RR 8
#define EPSV 0.1f
#define INV_EPS 10.0f
#define LOG2E 1.4426950408889634f
#define LN2 0.6931471805599453f
#define K2E (INV_EPS * LOG2E)   // exp(x*INV_EPS) = exp2(x*K2E)

typedef unsigned short ushort_t;
typedef __attribute__((ext_vector_type(8))) short bf16x8;
typedef __attribute__((ext_vector_type(4))) float f32x4;
typedef __attribute__((ext_vector_type(4))) unsigned int u32x4;
typedef __attribute__((ext_vector_type(2))) unsigned int u32x2;

// base-2 softplus: g(t) = max(t,0) + log2(1 + 2^-|t|), t = z*log2e; g = softplus(z)*log2e
__device__ __forceinline__ float g2(float t) {
    return fmaxf(t, 0.f) + __log2f(1.f + __builtin_amdgcn_exp2f(-fabsf(t)));
}
__device__ __forceinline__ ushort_t f2b(float f) {  // fp32 -> bf16 RNE
    unsigned u = __float_as_uint(f);
    return (ushort_t)((u + 0x7fffu + ((u >> 16) & 1u)) >> 16);
}
__device__ __forceinline__ float b2f(ushort_t h) {
    return __uint_as_float(((unsigned)h) << 16);
}
__device__ __forceinline__ unsigned pk2(float a, float b) {  // 2x fp32 -> packed bf16x2
    __hip_bfloat162 h = __float22bfloat162_rn(make_float2(a, b));
    return *reinterpret_cast<unsigned*>(&h);
}

// ---- K0 prep: Wt bf16 W^T (unscaled); XWxb=(X@Wx+b0)*log2e, YWyb=(Y@Wy)*log2e (bf16);
//      b1e=b1*log2e, b2e=b2*log2e, WoutE=Wout*ln2 (fp32) ----
__global__ __launch_bounds__(256) void prep_kernel(
    const float* __restrict__ X, const float* __restrict__ Y,
    const float* __restrict__ Wx, const float* __restrict__ Wy,
    const float* __restrict__ b0, const float* __restrict__ W1, const float* __restrict__ W2,
    const float* __restrict__ b1, const float* __restrict__ b2, const float* __restrict__ Wout,
    ushort_t* __restrict__ Wt1b, ushort_t* __restrict__ Wt2b,
    ushort_t* __restrict__ XWxb, ushort_t* __restrict__ YWyb,
    float* __restrict__ b1e, float* __restrict__ b2e, float* __restrict__ WoutE) {
    int gid = blockIdx.x * 256 + threadIdx.x;
    if (gid < 32768) {
        int sel = gid >> 14;
        int idx = gid & 16383;                  // n*128 + k
        int n = idx >> 7, k = idx & 127;
        (sel ? Wt2b : Wt1b)[idx] = f2b((sel ? W2 : W1)[k * HH + n]);
    } else if (gid < 98304) {
        int g = gid - 32768;
        int i = g >> 7, h = g & 127;
        float s = b0[h];
#pragma unroll
        for (int f = 0; f < FF; ++f) s += X[i * FF + f] * Wx[f * HH + h];
        XWxb[g] = f2b(s * LOG2E);
    } else if (gid < 163840) {
        int g = gid - 98304;
        int i = g >> 7, h = g & 127;
        float s = 0.f;
#pragma unroll
        for (int r = 0; r < RR; ++r) s += Y[i * RR + r] * Wy[r * HH + h];
        YWyb[g] = f2b(s * LOG2E);
    } else if (gid < 163968) {
        b1e[gid - 163840] = b1[gid - 163840] * LOG2E;
    } else if (gid < 164096) {
        b2e[gid - 163968] = b2[gid - 163968] * LOG2E;
    } else if (gid < 164224) {
        WoutE[gid - 164096] = Wout[gid - 164096] * LN2;
    }
}

// ---- K1: per (i, j-half): 4 chunks of 64 j; 2 barriers/chunk; layer1 h-owned
//      (hoisted weights), layer2 j-owned (in-wave psi, no psum) ----
__global__ __launch_bounds__(256, 2) void pair_kernel(
    const ushort_t* __restrict__ XWxb, const ushort_t* __restrict__ YWyb,
    const ushort_t* __restrict__ Wt1b, const ushort_t* __restrict__ Wt2b,
    const float* __restrict__ U, const float* __restrict__ Y,
    const float* __restrict__ b1e, const float* __restrict__ b2e,
    const float* __restrict__ WoutE, const float* __restrict__ bout,
    float* __restrict__ psi_arr, float* __restrict__ Mp, float* __restrict__ Sp) {
    __shared__ ushort_t Hs0[64 * HH];   // 16 KB (swizzled bf16, t-domain)
    __shared__ ushort_t Hs1[64 * HH];   // 16 KB
    __shared__ float redMS[8];

    const int i = blockIdx.x;
    const int half = blockIdx.y;
    const int t = threadIdx.x;
    const int wv = t >> 6;              // 0..3
    const int r16 = t & 15;
    const int g4 = (t >> 4) & 3;
    const int srow = t >> 4;            // 0..15 (staging row group)
    const int jl = wv * 16 + r16;       // layer-2 chunk-local j owned by this lane
    const float boutv = bout[0];

    // per-thread slice of XWx_i (+b0, *log2e), cols r16*8..+7
    float axf[8];
    {
        bf16x8 axv = *(const bf16x8*)&XWxb[i * HH + r16 * 8];
#pragma unroll
        for (int e = 0; e < 8; ++e) axf[e] = b2f((ushort_t)axv[e]);
    }
    // hoisted cost dot for this lane's j's: costr[c] = U[i] . Y[c*64 + jl]
    float costr[4];
    {
        const float4 u0 = *(const float4*)&U[i * RR];
        const float4 u1 = *(const float4*)&U[i * RR + 4];
#pragma unroll
        for (int c = 0; c < 4; ++c) {
            const int j = half * 256 + c * 64 + jl;
            const float4 y0 = *(const float4*)&Y[j * RR];
            const float4 y1 = *(const float4*)&Y[j * RR + 4];
            costr[c] = u0.x * y0.x + u0.y * y0.y + u0.z * y0.z + u0.w * y0.w +
                       u1.x * y1.x + u1.y * y1.y + u1.z * y1.z + u1.w * y1.w;
        }
    }
    // hoisted layer-1 weight fragments + bias (loop-invariant; wave owns h in [wv*32, +32))
    bf16x8 afr1[2][4];
#pragma unroll
    for (int mt = 0; mt < 2; ++mt)
#pragma unroll
        for (int ks = 0; ks < 4; ++ks)
            afr1[mt][ks] = *(const bf16x8*)&Wt1b[(wv * 32 + mt * 16 + r16) * HH + ks * 32 + g4 * 8];
    float4 bias1h[2];
    bias1h[0] = *(const float4*)&b1e[wv * 32 + g4 * 4];
    bias1h[1] = *(const float4*)&b1e[wv * 32 + 16 + g4 * 4];

    float m_l = -INFINITY, s_l = 0.f;   // online LSE (g4==0 lanes)
    bf16x8 pf[4];                       // prefetched YWy rows for current chunk

    // stage H0 for chunk at jb (from pf regs): g2(axf+y), swizzled bf16
    auto stage = [&](ushort_t* dst) {
#pragma unroll
        for (int s = 0; s < 4; ++s) {
            const int p = s * 16 + srow;
            const bf16x8 yv = pf[s];
            unsigned pk[4];
#pragma unroll
            for (int e = 0; e < 4; ++e) {
                float v0 = g2(axf[2 * e]     + b2f((ushort_t)yv[2 * e]));
                float v1 = g2(axf[2 * e + 1] + b2f((ushort_t)yv[2 * e + 1]));
                pk[e] = pk2(v0, v1);
            }
            *(u32x4*)&dst[p * HH + ((r16 ^ (p & 7)) << 3)] = *(u32x4*)pk;
        }
    };

    // prologue: prefetch + stage chunk 0
#pragma unroll
    for (int s = 0; s < 4; ++s)
        pf[s] = *(const bf16x8*)&YWyb[(half * 256 + s * 16 + srow) * HH + r16 * 8];
    stage(Hs0);
    __syncthreads();                    // A(0)

#pragma unroll
    for (int c = 0; c < 4; ++c) {
        const int j0 = half * 256 + c * 64;
        // prefetch next chunk's YWy early; latency hides under both layers
        if (c < 3) {
#pragma unroll
            for (int s = 0; s < 4; ++s)
                pf[s] = *(const bf16x8*)&YWyb[(j0 + 64 + s * 16 + srow) * HH + r16 * 8];
        }
        // ---- layer 1 (h-owned): t1 = W1t @ g(t0) + b1e, D[m=h1][n=j] ----
        f32x4 acc[2][4];
#pragma unroll
        for (int mt = 0; mt < 2; ++mt)
#pragma unroll
            for (int nt = 0; nt < 4; ++nt) {
                acc[mt][nt][0] = bias1h[mt].x; acc[mt][nt][1] = bias1h[mt].y;
                acc[mt][nt][2] = bias1h[mt].z; acc[mt][nt][3] = bias1h[mt].w;
            }
#pragma unroll
        for (int ks = 0; ks < 4; ++ks) {
            const int kb = ks * 32 + g4 * 8;
#pragma unroll
            for (int nt = 0; nt < 4; ++nt) {
                const int j = nt * 16 + r16;
                bf16x8 bfr = *(const bf16x8*)&Hs0[j * HH + (kb ^ ((j & 7) << 3))];
                acc[0][nt] = __builtin_amdgcn_mfma_f32_16x16x32_bf16(afr1[0][ks], bfr, acc[0][nt], 0, 0, 0);
                acc[1][nt] = __builtin_amdgcn_mfma_f32_16x16x32_bf16(afr1[1][ks], bfr, acc[1][nt], 0, 0, 0);
            }
        }
        // store H1[j][h1] = g2(t1) bf16 swizzled (4 consecutive h1 -> b64)
#pragma unroll
        for (int mt = 0; mt < 2; ++mt) {
            const int hb = wv * 32 + mt * 16 + g4 * 4;
#pragma unroll
            for (int nt = 0; nt < 4; ++nt) {
                const int j = nt * 16 + r16;
                u32x2 wv2;
                wv2[0] = pk2(g2(acc[mt][nt][0]), g2(acc[mt][nt][1]));
                wv2[1] = pk2(g2(acc[mt][nt][2]), g2(acc[mt][nt][3]));
                *(u32x2*)&Hs1[j * HH + (hb ^ ((j & 7) << 3))] = wv2;
            }
        }
        __syncthreads();                // X: H1 ready (also orders L2(c-1) reads)
        // ---- layer 2 (j-owned): lane's col j = jl; all 128 h2 in acc2[8] ----
        {
            bf16x8 b2r[4];
#pragma unroll
            for (int ks = 0; ks < 4; ++ks)
                b2r[ks] = *(const bf16x8*)&Hs1[jl * HH + ((ks * 32 + g4 * 8) ^ ((jl & 7) << 3))];
            f32x4 acc2[8];
#pragma unroll
            for (int mt = 0; mt < 8; ++mt) {
                float4 bb = *(const float4*)&b2e[mt * 16 + g4 * 4];
                acc2[mt][0] = bb.x; acc2[mt][1] = bb.y; acc2[mt][2] = bb.z; acc2[mt][3] = bb.w;
            }
#pragma unroll
            for (int ks = 0; ks < 4; ++ks)
#pragma unroll
                for (int mt = 0; mt < 8; ++mt) {
                    bf16x8 afr2 = *(const bf16x8*)&Wt2b[(mt * 16 + r16) * HH + ks * 32 + g4 * 8];
                    acc2[mt] = __builtin_amdgcn_mfma_f32_16x16x32_bf16(afr2, b2r[ks], acc2[mt], 0, 0, 0);
                }
            // psi_j = bout + sum_h g2(t2[h][jl]) * WoutE[h]; in-wave reduce over g4 groups
            float part = 0.f;
#pragma unroll
            for (int mt = 0; mt < 8; ++mt) {
                float4 wo = *(const float4*)&WoutE[mt * 16 + g4 * 4];
                part += g2(acc2[mt][0]) * wo.x + g2(acc2[mt][1]) * wo.y +
                        g2(acc2[mt][2]) * wo.z + g2(acc2[mt][3]) * wo.w;
            }
            part += __shfl_xor(part, 16);
            part += __shfl_xor(part, 32);
            if (g4 == 0) {
                const float psi = part + boutv;
                const int j = j0 + jl;
                if (j == i) psi_arr[i] = psi;
                const float sv = costr[c] - psi;
                const float mn = fmaxf(m_l, sv);
                s_l = s_l * __builtin_amdgcn_exp2f((m_l - mn) * K2E) +
                      __builtin_amdgcn_exp2f((sv - mn) * K2E);
                m_l = mn;
            }
        }
        // ---- stage next chunk (Hs0 reads all finished before X) + barrier A ----
        if (c < 3) {
            stage(Hs0);
            __syncthreads();            // A(c+1): orders L2(c) Hs1-reads vs L1(c+1) writes too
        }
    }
    // ---- wave-local (m,s) reduce; cross-wave combine once ----
    float M = m_l;
#pragma unroll
    for (int o = 1; o < 64; o <<= 1) M = fmaxf(M, __shfl_xor(M, o));
    float S = s_l * __builtin_amdgcn_exp2f((m_l - M) * K2E);
#pragma unroll
    for (int o = 1; o < 64; o <<= 1) S += __shfl_xor(S, o);
    if ((t & 63) == 0) { redMS[wv * 2] = M; redMS[wv * 2 + 1] = S; }
    __syncthreads();
    if (t == 0) {
        float Mg = redMS[0];
#pragma unroll
        for (int q = 1; q < 4; ++q) Mg = fmaxf(Mg, redMS[q * 2]);
        float S2 = 0.f;
#pragma unroll
        for (int q = 0; q < 4; ++q)
            S2 += redMS[q * 2 + 1] * __builtin_amdgcn_exp2f((redMS[q * 2] - Mg) * K2E);
        Mp[i * 2 + half] = Mg;
        Sp[i * 2 + half] = S2;
    }
}

// ---- K2: combine per-half partials -> phi_i; total = mean(phi) + mean(psi) ----
__global__ __launch_bounds__(512) void finalize_kernel(
    const float* __restrict__ psi_arr, const float* __restrict__ Mp,
    const float* __restrict__ Sp, float* __restrict__ out) {
    __shared__ float red[8];
    const int t = threadIdx.x;  // = i
    const float M0 = Mp[2 * t], M1 = Mp[2 * t + 1];
    const float S0 = Sp[2 * t], S1 = Sp[2 * t + 1];
    const float Mg = fmaxf(M0, M1);
    const float S = S0 * __expf((M0 - Mg) * INV_EPS) + S1 * __expf((M1 - Mg) * INV_EPS);
    const float phi = EPSV * (__logf(S) - __logf((float)NN)) + Mg;
    float v = phi + psi_arr[t];
#pragma unroll
    for (int o = 1; o < 64; o <<= 1) v += __shfl_xor(v, o);
    if ((t & 63) == 0) red[t >> 6] = v;
    __syncthreads();
    if (t == 0) {
        float tot = 0.f;
#pragma unroll
        for (int w = 0; w < 8; ++w) tot += red[w];
        out[0] = tot / (float)NN;
    }
}

extern "C" void kernel_launch(void* const* d_in, const int* in_sizes, int n_in,
                              void* d_out, int out_size, void* d_ws, size_t ws_size,
                              hipStream_t stream) {
    (void)in_sizes; (void)n_in; (void)out_size; (void)ws_size;
    const float* X    = (const float*)d_in[0];
    const float* U    = (const float*)d_in[1];
    const float* Y    = (const float*)d_in[2];
    const float* Wx   = (const float*)d_in[3];
    const float* Wy   = (const float*)d_in[4];
    const float* b0   = (const float*)d_in[5];
    const float* W1   = (const float*)d_in[6];
    const float* b1   = (const float*)d_in[7];
    const float* W2   = (const float*)d_in[8];
    const float* b2   = (const float*)d_in[9];
    const float* Wout = (const float*)d_in[10];
    const float* bout = (const float*)d_in[11];
    float* out = (float*)d_out;

    char* ws = (char*)d_ws;
    ushort_t* Wt1b    = (ushort_t*)(ws);                   // 32 KB
    ushort_t* Wt2b    = (ushort_t*)(ws + 32768);           // 32 KB
    ushort_t* XWxb    = (ushort_t*)(ws + 65536);           // 128 KB
    ushort_t* YWyb    = (ushort_t*)(ws + 196608);          // 128 KB
    float*    psi_arr = (float*)(ws + 327680);             // 2 KB
    float*    Mp      = (float*)(ws + 329728);             // 4 KB
    float*    Sp      = (float*)(ws + 333824);             // 4 KB
    float*    b1e     = (float*)(ws + 337920);             // 512 B
    float*    b2e     = (float*)(ws + 338432);             // 512 B
    float*    WoutE   = (float*)(ws + 338944);             // 512 B

    prep_kernel<<<642, 256, 0, stream>>>(X, Y, Wx, Wy, b0, W1, W2, b1, b2, Wout,
                                         Wt1b, Wt2b, XWxb, YWyb, b1e, b2e, WoutE);
    pair_kernel<<<dim3(NN, 2), 256, 0, stream>>>(XWxb, YWyb, Wt1b, Wt2b, U, Y,
                                                 b1e, b2e, WoutE, bout, psi_arr, Mp, Sp);
    finalize_kernel<<<1, 512, 0, stream>>>(psi_arr, Mp, Sp, out);
}

// Round 11
// 56.693 us; speedup vs baseline: 1.6808x; 1.6808x over previous
//
#include <hip/hip_runtime.h>
#include <hip/hip_bf16.h>
#include <math.h>

#define NN 512
#define HH 128
#define FF 32
#define RR 8
#define EPSV 0.1f
#define INV_EPS 10.0f
#define LOG2E 1.4426950408889634f
#define LN2 0.6931471805599453f
#define K2E (INV_EPS * LOG2E)   // exp(x*INV_EPS) = exp2(x*K2E)

typedef unsigned short ushort_t;
typedef __attribute__((ext_vector_type(8))) short bf16x8;
typedef __attribute__((ext_vector_type(4))) float f32x4;
typedef __attribute__((ext_vector_type(4))) unsigned int u32x4;
typedef __attribute__((ext_vector_type(2))) unsigned int u32x2;

// base-2 softplus: g(t) = max(t,0) + log2(1 + 2^-|t|), t = z*log2e; g = softplus(z)*log2e
__device__ __forceinline__ float g2(float t) {
    return fmaxf(t, 0.f) + __log2f(1.f + __builtin_amdgcn_exp2f(-fabsf(t)));
}
__device__ __forceinline__ ushort_t f2b(float f) {  // fp32 -> bf16 RNE
    unsigned u = __float_as_uint(f);
    return (ushort_t)((u + 0x7fffu + ((u >> 16) & 1u)) >> 16);
}
__device__ __forceinline__ float b2f(ushort_t h) {
    return __uint_as_float(((unsigned)h) << 16);
}
__device__ __forceinline__ unsigned pk2(float a, float b) {  // 2x fp32 -> packed bf16x2
    __hip_bfloat162 h = __float22bfloat162_rn(make_float2(a, b));
    return *reinterpret_cast<unsigned*>(&h);
}

// ---- K0 prep: Wt bf16 W^T (unscaled); XWxb=(X@Wx+b0)*log2e, YWyb=(Y@Wy)*log2e (bf16);
//      b1e=b1*log2e, b2e=b2*log2e, WoutE=Wout*ln2 (fp32) ----
__global__ __launch_bounds__(256) void prep_kernel(
    const float* __restrict__ X, const float* __restrict__ Y,
    const float* __restrict__ Wx, const float* __restrict__ Wy,
    const float* __restrict__ b0, const float* __restrict__ W1, const float* __restrict__ W2,
    const float* __restrict__ b1, const float* __restrict__ b2, const float* __restrict__ Wout,
    ushort_t* __restrict__ Wt1b, ushort_t* __restrict__ Wt2b,
    ushort_t* __restrict__ XWxb, ushort_t* __restrict__ YWyb,
    float* __restrict__ b1e, float* __restrict__ b2e, float* __restrict__ WoutE) {
    int gid = blockIdx.x * 256 + threadIdx.x;
    if (gid < 32768) {
        int sel = gid >> 14;
        int idx = gid & 16383;                  // n*128 + k
        int n = idx >> 7, k = idx & 127;
        (sel ? Wt2b : Wt1b)[idx] = f2b((sel ? W2 : W1)[k * HH + n]);
    } else if (gid < 98304) {
        int g = gid - 32768;
        int i = g >> 7, h = g & 127;
        float s = b0[h];
#pragma unroll
        for (int f = 0; f < FF; ++f) s += X[i * FF + f] * Wx[f * HH + h];
        XWxb[g] = f2b(s * LOG2E);
    } else if (gid < 163840) {
        int g = gid - 98304;
        int i = g >> 7, h = g & 127;
        float s = 0.f;
#pragma unroll
        for (int r = 0; r < RR; ++r) s += Y[i * RR + r] * Wy[r * HH + h];
        YWyb[g] = f2b(s * LOG2E);
    } else if (gid < 163968) {
        b1e[gid - 163840] = b1[gid - 163840] * LOG2E;
    } else if (gid < 164096) {
        b2e[gid - 163968] = b2[gid - 163968] * LOG2E;
    } else if (gid < 164224) {
        WoutE[gid - 164096] = Wout[gid - 164096] * LN2;
    }
}

// Flipped layer (R9-proven): acc[mt][nt] = Wt(A) @ Hin(B) + bias; D[m=h_out][n=j].
// A-frags batch-loaded from global Wt at top (L1-hot), B-frags from swizzled LDS.
__device__ __forceinline__ void layer_flip(
    const ushort_t* __restrict__ Hin, const ushort_t* __restrict__ WtG,
    const float* __restrict__ bias, f32x4 acc[2][4], int r16, int g4, int wv) {
    const int hbase = wv * 32 + g4 * 4;
#pragma unroll
    for (int mt = 0; mt < 2; ++mt) {
        float4 bb = *(const float4*)&bias[hbase + mt * 16];
#pragma unroll
        for (int nt = 0; nt < 4; ++nt) {
            acc[mt][nt][0] = bb.x; acc[mt][nt][1] = bb.y;
            acc[mt][nt][2] = bb.z; acc[mt][nt][3] = bb.w;
        }
    }
    bf16x8 afr[2][4];
#pragma unroll
    for (int mt = 0; mt < 2; ++mt)
#pragma unroll
        for (int ks = 0; ks < 4; ++ks)
            afr[mt][ks] = *(const bf16x8*)&WtG[(wv * 32 + mt * 16 + r16) * HH + ks * 32 + g4 * 8];
#pragma unroll
    for (int ks = 0; ks < 4; ++ks) {
        const int kb = ks * 32 + g4 * 8;
#pragma unroll
        for (int nt = 0; nt < 4; ++nt) {
            const int j = nt * 16 + r16;
            bf16x8 bfr = *(const bf16x8*)&Hin[j * HH + (kb ^ ((j & 7) << 3))];
            acc[0][nt] = __builtin_amdgcn_mfma_f32_16x16x32_bf16(afr[0][ks], bfr, acc[0][nt], 0, 0, 0);
            acc[1][nt] = __builtin_amdgcn_mfma_f32_16x16x32_bf16(afr[1][ks], bfr, acc[1][nt], 0, 0, 0);
        }
    }
}

// ---- K1: per (i, j-half): 4 chunks of 64 j; reg-prefetch YWy; layer-1 weights hoisted ----
__global__ __launch_bounds__(256, 2) void pair_kernel(
    const ushort_t* __restrict__ XWxb, const ushort_t* __restrict__ YWyb,
    const ushort_t* __restrict__ Wt1b, const ushort_t* __restrict__ Wt2b,
    const float* __restrict__ U, const float* __restrict__ Y,
    const float* __restrict__ b1e, const float* __restrict__ b2e,
    const float* __restrict__ WoutE, const float* __restrict__ bout,
    float* __restrict__ psi_arr, float* __restrict__ Mp, float* __restrict__ Sp) {
    __shared__ ushort_t Hs0[64 * HH];   // 16 KB (swizzled bf16, t-domain)
    __shared__ ushort_t Hs1[64 * HH];   // 16 KB
    __shared__ float psum[4][64];       // per-wave psi partials

    const int i = blockIdx.x;
    const int half = blockIdx.y;
    const int t = threadIdx.x;
    const int wv = t >> 6;
    const int r16 = t & 15;
    const int g4 = (t >> 4) & 3;
    const int srow = t >> 4;            // 0..15 (staging row group)
    const float boutv = bout[0];

    // per-thread slice of XWx_i (+b0, *log2e), cols r16*8..+7
    float axf[8];
    {
        bf16x8 axv = *(const bf16x8*)&XWxb[i * HH + r16 * 8];
#pragma unroll
        for (int e = 0; e < 8; ++e) axf[e] = b2f((ushort_t)axv[e]);
    }
    // hoisted cost dot: costr[c] = U[i] . Y[j0(c) + (t&63)]
    float costr[4];
    {
        const float4 u0 = *(const float4*)&U[i * RR];
        const float4 u1 = *(const float4*)&U[i * RR + 4];
#pragma unroll
        for (int c = 0; c < 4; ++c) {
            const int j = half * 256 + c * 64 + (t & 63);
            const float4 y0 = *(const float4*)&Y[j * RR];
            const float4 y1 = *(const float4*)&Y[j * RR + 4];
            costr[c] = u0.x * y0.x + u0.y * y0.y + u0.z * y0.z + u0.w * y0.w +
                       u1.x * y1.x + u1.y * y1.y + u1.z * y1.z + u1.w * y1.w;
        }
    }
    // hoisted layer-1 weight fragments + bias (loop-invariant; wave owns h in [wv*32,+32))
    bf16x8 afr1[2][4];
#pragma unroll
    for (int mt = 0; mt < 2; ++mt)
#pragma unroll
        for (int ks = 0; ks < 4; ++ks)
            afr1[mt][ks] = *(const bf16x8*)&Wt1b[(wv * 32 + mt * 16 + r16) * HH + ks * 32 + g4 * 8];
    float4 bias1h[2];
    bias1h[0] = *(const float4*)&b1e[wv * 32 + g4 * 4];
    bias1h[1] = *(const float4*)&b1e[wv * 32 + 16 + g4 * 4];
    // hoisted epilogue weights (loop-invariant)
    float4 woutr[2];
    woutr[0] = *(const float4*)&WoutE[wv * 32 + g4 * 4];
    woutr[1] = *(const float4*)&WoutE[wv * 32 + 16 + g4 * 4];

    float m_l = -INFINITY, s_l = 0.f;   // online LSE state (t<64 lanes)
    f32x4 acc[2][4];
    bf16x8 pf[4];                       // prefetched YWy rows for current chunk

    // prologue: prefetch chunk 0
#pragma unroll
    for (int s = 0; s < 4; ++s)
        pf[s] = *(const bf16x8*)&YWyb[(half * 256 + s * 16 + srow) * HH + r16 * 8];

#pragma unroll
    for (int c = 0; c < 4; ++c) {
        const int j0 = half * 256 + c * 64;
        // ---- stage H0 from prefetched regs: g2(axf + yv), swizzled bf16 ----
#pragma unroll
        for (int s = 0; s < 4; ++s) {
            const int p = s * 16 + srow;
            const bf16x8 yv = pf[s];
            unsigned pk[4];
#pragma unroll
            for (int e = 0; e < 4; ++e) {
                float v0 = g2(axf[2 * e]     + b2f((ushort_t)yv[2 * e]));
                float v1 = g2(axf[2 * e + 1] + b2f((ushort_t)yv[2 * e + 1]));
                pk[e] = pk2(v0, v1);
            }
            *(u32x4*)&Hs0[p * HH + ((r16 ^ (p & 7)) << 3)] = *(u32x4*)pk;
        }
        __syncthreads();                // A: H0 ready
        // issue next chunk's prefetch now; latency hides under both layers
        if (c < 3) {
#pragma unroll
            for (int s = 0; s < 4; ++s)
                pf[s] = *(const bf16x8*)&YWyb[(j0 + 64 + s * 16 + srow) * HH + r16 * 8];
        }
        // ---- layer 1 (h-owned, hoisted weights): t1 = W1t @ g(t0) + b1e ----
#pragma unroll
        for (int mt = 0; mt < 2; ++mt)
#pragma unroll
            for (int nt = 0; nt < 4; ++nt) {
                acc[mt][nt][0] = bias1h[mt].x; acc[mt][nt][1] = bias1h[mt].y;
                acc[mt][nt][2] = bias1h[mt].z; acc[mt][nt][3] = bias1h[mt].w;
            }
#pragma unroll
        for (int ks = 0; ks < 4; ++ks) {
            const int kb = ks * 32 + g4 * 8;
#pragma unroll
            for (int nt = 0; nt < 4; ++nt) {
                const int j = nt * 16 + r16;
                bf16x8 bfr = *(const bf16x8*)&Hs0[j * HH + (kb ^ ((j & 7) << 3))];
                acc[0][nt] = __builtin_amdgcn_mfma_f32_16x16x32_bf16(afr1[0][ks], bfr, acc[0][nt], 0, 0, 0);
                acc[1][nt] = __builtin_amdgcn_mfma_f32_16x16x32_bf16(afr1[1][ks], bfr, acc[1][nt], 0, 0, 0);
            }
        }
        // store H1[j][h1] = g2(t1) bf16 swizzled (4 consecutive h1 -> b64)
#pragma unroll
        for (int mt = 0; mt < 2; ++mt) {
            const int hb = wv * 32 + mt * 16 + g4 * 4;
#pragma unroll
            for (int nt = 0; nt < 4; ++nt) {
                const int j = nt * 16 + r16;
                u32x2 wv2;
                wv2[0] = pk2(g2(acc[mt][nt][0]), g2(acc[mt][nt][1]));
                wv2[1] = pk2(g2(acc[mt][nt][2]), g2(acc[mt][nt][3]));
                *(u32x2*)&Hs1[j * HH + (hb ^ ((j & 7) << 3))] = wv2;
            }
        }
        __syncthreads();                // X: H1 ready
        // ---- layer 2 (h-owned, R9-proven batch loads): t2 = W2t @ g(t1) + b2e ----
        layer_flip(Hs1, Wt2b, b2e, acc, r16, g4, wv);
        // ---- epilogue in-register: psi partial = sum_h g2(t2)*WoutE[h] ----
        {
            float part[4] = {0.f, 0.f, 0.f, 0.f};
#pragma unroll
            for (int mt = 0; mt < 2; ++mt) {
                const float wr[4] = {woutr[mt].x, woutr[mt].y, woutr[mt].z, woutr[mt].w};
#pragma unroll
                for (int r = 0; r < 4; ++r) {
                    const float wgt = wr[r];
#pragma unroll
                    for (int nt = 0; nt < 4; ++nt)
                        part[nt] += g2(acc[mt][nt][r]) * wgt;
                }
            }
#pragma unroll
            for (int nt = 0; nt < 4; ++nt) {
                part[nt] += __shfl_xor(part[nt], 16);
                part[nt] += __shfl_xor(part[nt], 32);
            }
            if (g4 == 0) {
#pragma unroll
                for (int nt = 0; nt < 4; ++nt) psum[wv][nt * 16 + r16] = part[nt];
            }
        }
        __syncthreads();                // Y: psum ready
        // ---- LSE update: t<64 lanes, one j each ----
        if (t < 64) {
            const float psi = boutv + psum[0][t] + psum[1][t] + psum[2][t] + psum[3][t];
            const int j = j0 + t;
            const float sv = costr[c] - psi;
            const float mn = fmaxf(m_l, sv);
            s_l = s_l * __builtin_amdgcn_exp2f((m_l - mn) * K2E) +
                  __builtin_amdgcn_exp2f((sv - mn) * K2E);
            m_l = mn;
            if (j == i) psi_arr[i] = psi;
        }
        // psum next written after X_{c+1}, ordered after every lane's read above
    }
    // ---- combine t<64 lanes' (m,s); write block partial ----
    if (t < 64) {
        float M = m_l;
#pragma unroll
        for (int o = 1; o < 64; o <<= 1) M = fmaxf(M, __shfl_xor(M, o));
        float S = s_l * __builtin_amdgcn_exp2f((m_l - M) * K2E);
#pragma unroll
        for (int o = 1; o < 64; o <<= 1) S += __shfl_xor(S, o);
        if (t == 0) {
            Mp[i * 2 + half] = M;
            Sp[i * 2 + half] = S;
        }
    }
}

// ---- K2: combine per-half partials -> phi_i; total = mean(phi) + mean(psi) ----
__global__ __launch_bounds__(512) void finalize_kernel(
    const float* __restrict__ psi_arr, const float* __restrict__ Mp,
    const float* __restrict__ Sp, float* __restrict__ out) {
    __shared__ float red[8];
    const int t = threadIdx.x;  // = i
    const float M0 = Mp[2 * t], M1 = Mp[2 * t + 1];
    const float S0 = Sp[2 * t], S1 = Sp[2 * t + 1];
    const float Mg = fmaxf(M0, M1);
    const float S = S0 * __expf((M0 - Mg) * INV_EPS) + S1 * __expf((M1 - Mg) * INV_EPS);
    const float phi = EPSV * (__logf(S) - __logf((float)NN)) + Mg;
    float v = phi + psi_arr[t];
#pragma unroll
    for (int o = 1; o < 64; o <<= 1) v += __shfl_xor(v, o);
    if ((t & 63) == 0) red[t >> 6] = v;
    __syncthreads();
    if (t == 0) {
        float tot = 0.f;
#pragma unroll
        for (int w = 0; w < 8; ++w) tot += red[w];
        out[0] = tot / (float)NN;
    }
}

extern "C" void kernel_launch(void* const* d_in, const int* in_sizes, int n_in,
                              void* d_out, int out_size, void* d_ws, size_t ws_size,
                              hipStream_t stream) {
    (void)in_sizes; (void)n_in; (void)out_size; (void)ws_size;
    const float* X    = (const float*)d_in[0];
    const float* U    = (const float*)d_in[1];
    const float* Y    = (const float*)d_in[2];
    const float* Wx   = (const float*)d_in[3];
    const float* Wy   = (const float*)d_in[4];
    const float* b0   = (const float*)d_in[5];
    const float* W1   = (const float*)d_in[6];
    const float* b1   = (const float*)d_in[7];
    const float* W2   = (const float*)d_in[8];
    const float* b2   = (const float*)d_in[9];
    const float* Wout = (const float*)d_in[10];
    const float* bout = (const float*)d_in[11];
    float* out = (float*)d_out;

    char* ws = (char*)d_ws;
    ushort_t* Wt1b    = (ushort_t*)(ws);                   // 32 KB
    ushort_t* Wt2b    = (ushort_t*)(ws + 32768);           // 32 KB
    ushort_t* XWxb    = (ushort_t*)(ws + 65536);           // 128 KB
    ushort_t* YWyb    = (ushort_t*)(ws + 196608);          // 128 KB
    float*    psi_arr = (float*)(ws + 327680);             // 2 KB
    float*    Mp      = (float*)(ws + 329728);             // 4 KB
    float*    Sp      = (float*)(ws + 333824);             // 4 KB
    float*    b1e     = (float*)(ws + 337920);             // 512 B
    float*    b2e     = (float*)(ws + 338432);             // 512 B
    float*    WoutE   = (float*)(ws + 338944);             // 512 B

    prep_kernel<<<642, 256, 0, stream>>>(X, Y, Wx, Wy, b0, W1, W2, b1, b2, Wout,
                                         Wt1b, Wt2b, XWxb, YWyb, b1e, b2e, WoutE);
    pair_kernel<<<dim3(NN, 2), 256, 0, stream>>>(XWxb, YWyb, Wt1b, Wt2b, U, Y,
                                                 b1e, b2e, WoutE, bout, psi_arr, Mp, Sp);
    finalize_kernel<<<1, 512, 0, stream>>>(psi_arr, Mp, Sp, out);
}

// Round 12
// 55.628 us; speedup vs baseline: 1.7130x; 1.0191x over previous
//
#include <hip/hip_runtime.h>
#include <hip/hip_bf16.h>
#include <math.h>

#define NN 512
#define HH 128
#define FF 32
#define RR 8
#define EPSV 0.1f
#define INV_EPS 10.0f
#define LOG2E 1.4426950408889634f
#define LN2 0.6931471805599453f
#define K2E (INV_EPS * LOG2E)   // exp(x*INV_EPS) = exp2(x*K2E)

typedef unsigned short ushort_t;
typedef __attribute__((ext_vector_type(8))) short bf16x8;
typedef __attribute__((ext_vector_type(4))) float f32x4;
typedef __attribute__((ext_vector_type(4))) unsigned int u32x4;
typedef __attribute__((ext_vector_type(2))) unsigned int u32x2;

// base-2 softplus: g(t) = max(t,0) + log2(1 + 2^-|t|), t = z*log2e; g = softplus(z)*log2e
__device__ __forceinline__ float g2(float t) {
    return fmaxf(t, 0.f) + __log2f(1.f + __builtin_amdgcn_exp2f(-fabsf(t)));
}
__device__ __forceinline__ ushort_t f2b(float f) {  // fp32 -> bf16 RNE
    unsigned u = __float_as_uint(f);
    return (ushort_t)((u + 0x7fffu + ((u >> 16) & 1u)) >> 16);
}
__device__ __forceinline__ float b2f(ushort_t h) {
    return __uint_as_float(((unsigned)h) << 16);
}
__device__ __forceinline__ unsigned pk2(float a, float b) {  // 2x fp32 -> packed bf16x2
    __hip_bfloat162 h = __float22bfloat162_rn(make_float2(a, b));
    return *reinterpret_cast<unsigned*>(&h);
}

// ---- K0 prep: Wt bf16 W^T (unscaled); XWxb=(X@Wx+b0)*log2e, YWyb=(Y@Wy)*log2e (bf16);
//      b1e=b1*log2e, b2e=b2*log2e, WoutE=Wout*ln2 (fp32) ----
__global__ __launch_bounds__(256) void prep_kernel(
    const float* __restrict__ X, const float* __restrict__ Y,
    const float* __restrict__ Wx, const float* __restrict__ Wy,
    const float* __restrict__ b0, const float* __restrict__ W1, const float* __restrict__ W2,
    const float* __restrict__ b1, const float* __restrict__ b2, const float* __restrict__ Wout,
    ushort_t* __restrict__ Wt1b, ushort_t* __restrict__ Wt2b,
    ushort_t* __restrict__ XWxb, ushort_t* __restrict__ YWyb,
    float* __restrict__ b1e, float* __restrict__ b2e, float* __restrict__ WoutE) {
    int gid = blockIdx.x * 256 + threadIdx.x;
    if (gid < 32768) {
        int sel = gid >> 14;
        int idx = gid & 16383;                  // n*128 + k
        int n = idx >> 7, k = idx & 127;
        (sel ? Wt2b : Wt1b)[idx] = f2b((sel ? W2 : W1)[k * HH + n]);
    } else if (gid < 98304) {
        int g = gid - 32768;
        int i = g >> 7, h = g & 127;
        float s = b0[h];
#pragma unroll
        for (int f = 0; f < FF; ++f) s += X[i * FF + f] * Wx[f * HH + h];
        XWxb[g] = f2b(s * LOG2E);
    } else if (gid < 163840) {
        int g = gid - 98304;
        int i = g >> 7, h = g & 127;
        float s = 0.f;
#pragma unroll
        for (int r = 0; r < RR; ++r) s += Y[i * RR + r] * Wy[r * HH + h];
        YWyb[g] = f2b(s * LOG2E);
    } else if (gid < 163968) {
        b1e[gid - 163840] = b1[gid - 163840] * LOG2E;
    } else if (gid < 164096) {
        b2e[gid - 163968] = b2[gid - 163968] * LOG2E;
    } else if (gid < 164224) {
        WoutE[gid - 164096] = Wout[gid - 164096] * LN2;
    }
}

// Flipped layer (R9-proven): acc[mt][nt] = Wt(A) @ Hin(B) + bias; D[m=h_out][n=j].
__device__ __forceinline__ void layer_flip(
    const ushort_t* __restrict__ Hin, const ushort_t* __restrict__ WtG,
    const float* __restrict__ bias, f32x4 acc[2][4], int r16, int g4, int wv) {
    const int hbase = wv * 32 + g4 * 4;
#pragma unroll
    for (int mt = 0; mt < 2; ++mt) {
        float4 bb = *(const float4*)&bias[hbase + mt * 16];
#pragma unroll
        for (int nt = 0; nt < 4; ++nt) {
            acc[mt][nt][0] = bb.x; acc[mt][nt][1] = bb.y;
            acc[mt][nt][2] = bb.z; acc[mt][nt][3] = bb.w;
        }
    }
    bf16x8 afr[2][4];
#pragma unroll
    for (int mt = 0; mt < 2; ++mt)
#pragma unroll
        for (int ks = 0; ks < 4; ++ks)
            afr[mt][ks] = *(const bf16x8*)&WtG[(wv * 32 + mt * 16 + r16) * HH + ks * 32 + g4 * 8];
#pragma unroll
    for (int ks = 0; ks < 4; ++ks) {
        const int kb = ks * 32 + g4 * 8;
#pragma unroll
        for (int nt = 0; nt < 4; ++nt) {
            const int j = nt * 16 + r16;
            bf16x8 bfr = *(const bf16x8*)&Hin[j * HH + (kb ^ ((j & 7) << 3))];
            acc[0][nt] = __builtin_amdgcn_mfma_f32_16x16x32_bf16(afr[0][ks], bfr, acc[0][nt], 0, 0, 0);
            acc[1][nt] = __builtin_amdgcn_mfma_f32_16x16x32_bf16(afr[1][ks], bfr, acc[1][nt], 0, 0, 0);
        }
    }
}

// ---- K1: per (i, j-half): 4 chunks of 64 j; 2 barriers/chunk; LSE fully post-loop ----
__global__ __launch_bounds__(256, 2) void pair_kernel(
    const ushort_t* __restrict__ XWxb, const ushort_t* __restrict__ YWyb,
    const ushort_t* __restrict__ Wt1b, const ushort_t* __restrict__ Wt2b,
    const float* __restrict__ U, const float* __restrict__ Y,
    const float* __restrict__ b1e, const float* __restrict__ b2e,
    const float* __restrict__ WoutE, const float* __restrict__ bout,
    float* __restrict__ psi_arr, float* __restrict__ Mp, float* __restrict__ Sp) {
    __shared__ ushort_t Hs0[64 * HH];   // 16 KB (swizzled bf16, t-domain)
    __shared__ ushort_t Hs1[64 * HH];   // 16 KB
    __shared__ float psum[4][4][64];    // [chunk][wave][j] psi partials, 4 KB

    const int i = blockIdx.x;
    const int half = blockIdx.y;
    const int t = threadIdx.x;
    const int wv = t >> 6;
    const int r16 = t & 15;
    const int g4 = (t >> 4) & 3;
    const int srow = t >> 4;            // 0..15 (staging row group)
    const float boutv = bout[0];

    // per-thread slice of XWx_i (+b0, *log2e), cols r16*8..+7
    float axf[8];
    {
        bf16x8 axv = *(const bf16x8*)&XWxb[i * HH + r16 * 8];
#pragma unroll
        for (int e = 0; e < 8; ++e) axf[e] = b2f((ushort_t)axv[e]);
    }
    // hoisted cost dot: costr[c] = U[i] . Y[j0(c) + (t&63)]
    float costr[4];
    {
        const float4 u0 = *(const float4*)&U[i * RR];
        const float4 u1 = *(const float4*)&U[i * RR + 4];
#pragma unroll
        for (int c = 0; c < 4; ++c) {
            const int j = half * 256 + c * 64 + (t & 63);
            const float4 y0 = *(const float4*)&Y[j * RR];
            const float4 y1 = *(const float4*)&Y[j * RR + 4];
            costr[c] = u0.x * y0.x + u0.y * y0.y + u0.z * y0.z + u0.w * y0.w +
                       u1.x * y1.x + u1.y * y1.y + u1.z * y1.z + u1.w * y1.w;
        }
    }
    // hoisted layer-1 weight fragments + bias (loop-invariant; wave owns h in [wv*32,+32))
    bf16x8 afr1[2][4];
#pragma unroll
    for (int mt = 0; mt < 2; ++mt)
#pragma unroll
        for (int ks = 0; ks < 4; ++ks)
            afr1[mt][ks] = *(const bf16x8*)&Wt1b[(wv * 32 + mt * 16 + r16) * HH + ks * 32 + g4 * 8];
    float4 bias1h[2];
    bias1h[0] = *(const float4*)&b1e[wv * 32 + g4 * 4];
    bias1h[1] = *(const float4*)&b1e[wv * 32 + 16 + g4 * 4];
    // hoisted epilogue weights (loop-invariant)
    float4 woutr[2];
    woutr[0] = *(const float4*)&WoutE[wv * 32 + g4 * 4];
    woutr[1] = *(const float4*)&WoutE[wv * 32 + 16 + g4 * 4];

    f32x4 acc[2][4];
    bf16x8 pf[4];                       // prefetched YWy rows for current chunk

    // prologue: prefetch chunk 0
#pragma unroll
    for (int s = 0; s < 4; ++s)
        pf[s] = *(const bf16x8*)&YWyb[(half * 256 + s * 16 + srow) * HH + r16 * 8];

#pragma unroll
    for (int c = 0; c < 4; ++c) {
        const int j0 = half * 256 + c * 64;
        // ---- stage H0 from prefetched regs: g2(axf + yv), swizzled bf16 ----
        // (Hs0 reads of chunk c-1 completed before barrier X(c-1))
#pragma unroll
        for (int s = 0; s < 4; ++s) {
            const int p = s * 16 + srow;
            const bf16x8 yv = pf[s];
            unsigned pk[4];
#pragma unroll
            for (int e = 0; e < 4; ++e) {
                float v0 = g2(axf[2 * e]     + b2f((ushort_t)yv[2 * e]));
                float v1 = g2(axf[2 * e + 1] + b2f((ushort_t)yv[2 * e + 1]));
                pk[e] = pk2(v0, v1);
            }
            *(u32x4*)&Hs0[p * HH + ((r16 ^ (p & 7)) << 3)] = *(u32x4*)pk;
        }
        __syncthreads();                // A: H0 ready (also orders L2(c-1) Hs1-reads)
        // issue next chunk's prefetch now; latency hides under both layers
        if (c < 3) {
#pragma unroll
            for (int s = 0; s < 4; ++s)
                pf[s] = *(const bf16x8*)&YWyb[(j0 + 64 + s * 16 + srow) * HH + r16 * 8];
        }
        // ---- layer 1 (h-owned, hoisted weights): t1 = W1t @ g(t0) + b1e ----
#pragma unroll
        for (int mt = 0; mt < 2; ++mt)
#pragma unroll
            for (int nt = 0; nt < 4; ++nt) {
                acc[mt][nt][0] = bias1h[mt].x; acc[mt][nt][1] = bias1h[mt].y;
                acc[mt][nt][2] = bias1h[mt].z; acc[mt][nt][3] = bias1h[mt].w;
            }
#pragma unroll
        for (int ks = 0; ks < 4; ++ks) {
            const int kb = ks * 32 + g4 * 8;
#pragma unroll
            for (int nt = 0; nt < 4; ++nt) {
                const int j = nt * 16 + r16;
                bf16x8 bfr = *(const bf16x8*)&Hs0[j * HH + (kb ^ ((j & 7) << 3))];
                acc[0][nt] = __builtin_amdgcn_mfma_f32_16x16x32_bf16(afr1[0][ks], bfr, acc[0][nt], 0, 0, 0);
                acc[1][nt] = __builtin_amdgcn_mfma_f32_16x16x32_bf16(afr1[1][ks], bfr, acc[1][nt], 0, 0, 0);
            }
        }
        // store H1[j][h1] = g2(t1) bf16 swizzled (4 consecutive h1 -> b64)
#pragma unroll
        for (int mt = 0; mt < 2; ++mt) {
            const int hb = wv * 32 + mt * 16 + g4 * 4;
#pragma unroll
            for (int nt = 0; nt < 4; ++nt) {
                const int j = nt * 16 + r16;
                u32x2 wv2;
                wv2[0] = pk2(g2(acc[mt][nt][0]), g2(acc[mt][nt][1]));
                wv2[1] = pk2(g2(acc[mt][nt][2]), g2(acc[mt][nt][3]));
                *(u32x2*)&Hs1[j * HH + (hb ^ ((j & 7) << 3))] = wv2;
            }
        }
        __syncthreads();                // X: H1 ready (also orders Hs0-reads vs stage(c+1))
        // ---- layer 2 (h-owned, batch loads): t2 = W2t @ g(t1) + b2e ----
        layer_flip(Hs1, Wt2b, b2e, acc, r16, g4, wv);
        // ---- epilogue in-register: psi partial -> chunk slab psum[c] ----
        {
            float part[4] = {0.f, 0.f, 0.f, 0.f};
#pragma unroll
            for (int mt = 0; mt < 2; ++mt) {
                const float wr[4] = {woutr[mt].x, woutr[mt].y, woutr[mt].z, woutr[mt].w};
#pragma unroll
                for (int r = 0; r < 4; ++r) {
                    const float wgt = wr[r];
#pragma unroll
                    for (int nt = 0; nt < 4; ++nt)
                        part[nt] += g2(acc[mt][nt][r]) * wgt;
                }
            }
#pragma unroll
            for (int nt = 0; nt < 4; ++nt) {
                part[nt] += __shfl_xor(part[nt], 16);
                part[nt] += __shfl_xor(part[nt], 32);
            }
            if (g4 == 0) {
#pragma unroll
                for (int nt = 0; nt < 4; ++nt) psum[c][wv][nt * 16 + r16] = part[nt];
            }
        }
        // no barrier here: psum[c] slab is read only after the final barrier
    }
    __syncthreads();                    // F: all psum slabs ready
    // ---- post-loop online LSE over 4 chunks (t<64 lanes, one j-column each) ----
    if (t < 64) {
        float m_l = -INFINITY, s_l = 0.f;
#pragma unroll
        for (int c = 0; c < 4; ++c) {
            const float psi = boutv + psum[c][0][t] + psum[c][1][t] +
                              psum[c][2][t] + psum[c][3][t];
            const int j = half * 256 + c * 64 + t;
            if (j == i) psi_arr[i] = psi;
            const float sv = costr[c] - psi;
            const float mn = fmaxf(m_l, sv);
            s_l = s_l * __builtin_amdgcn_exp2f((m_l - mn) * K2E) +
                  __builtin_amdgcn_exp2f((sv - mn) * K2E);
            m_l = mn;
        }
        float M = m_l;
#pragma unroll
        for (int o = 1; o < 64; o <<= 1) M = fmaxf(M, __shfl_xor(M, o));
        float S = s_l * __builtin_amdgcn_exp2f((m_l - M) * K2E);
#pragma unroll
        for (int o = 1; o < 64; o <<= 1) S += __shfl_xor(S, o);
        if (t == 0) {
            Mp[i * 2 + half] = M;
            Sp[i * 2 + half] = S;
        }
    }
}

// ---- K2: combine per-half partials -> phi_i; total = mean(phi) + mean(psi) ----
__global__ __launch_bounds__(512) void finalize_kernel(
    const float* __restrict__ psi_arr, const float* __restrict__ Mp,
    const float* __restrict__ Sp, float* __restrict__ out) {
    __shared__ float red[8];
    const int t = threadIdx.x;  // = i
    const float M0 = Mp[2 * t], M1 = Mp[2 * t + 1];
    const float S0 = Sp[2 * t], S1 = Sp[2 * t + 1];
    const float Mg = fmaxf(M0, M1);
    const float S = S0 * __expf((M0 - Mg) * INV_EPS) + S1 * __expf((M1 - Mg) * INV_EPS);
    const float phi = EPSV * (__logf(S) - __logf((float)NN)) + Mg;
    float v = phi + psi_arr[t];
#pragma unroll
    for (int o = 1; o < 64; o <<= 1) v += __shfl_xor(v, o);
    if ((t & 63) == 0) red[t >> 6] = v;
    __syncthreads();
    if (t == 0) {
        float tot = 0.f;
#pragma unroll
        for (int w = 0; w < 8; ++w) tot += red[w];
        out[0] = tot / (float)NN;
    }
}

extern "C" void kernel_launch(void* const* d_in, const int* in_sizes, int n_in,
                              void* d_out, int out_size, void* d_ws, size_t ws_size,
                              hipStream_t stream) {
    (void)in_sizes; (void)n_in; (void)out_size; (void)ws_size;
    const float* X    = (const float*)d_in[0];
    const float* U    = (const float*)d_in[1];
    const float* Y    = (const float*)d_in[2];
    const float* Wx   = (const float*)d_in[3];
    const float* Wy   = (const float*)d_in[4];
    const float* b0   = (const float*)d_in[5];
    const float* W1   = (const float*)d_in[6];
    const float* b1   = (const float*)d_in[7];
    const float* W2   = (const float*)d_in[8];
    const float* b2   = (const float*)d_in[9];
    const float* Wout = (const float*)d_in[10];
    const float* bout = (const float*)d_in[11];
    float* out = (float*)d_out;

    char* ws = (char*)d_ws;
    ushort_t* Wt1b    = (ushort_t*)(ws);                   // 32 KB
    ushort_t* Wt2b    = (ushort_t*)(ws + 32768);           // 32 KB
    ushort_t* XWxb    = (ushort_t*)(ws + 65536);           // 128 KB
    ushort_t* YWyb    = (ushort_t*)(ws + 196608);          // 128 KB
    float*    psi_arr = (float*)(ws + 327680);             // 2 KB
    float*    Mp      = (float*)(ws + 329728);             // 4 KB
    float*    Sp      = (float*)(ws + 333824);             // 4 KB
    float*    b1e     = (float*)(ws + 337920);             // 512 B
    float*    b2e     = (float*)(ws + 338432);             // 512 B
    float*    WoutE   = (float*)(ws + 338944);             // 512 B

    prep_kernel<<<642, 256, 0, stream>>>(X, Y, Wx, Wy, b0, W1, W2, b1, b2, Wout,
                                         Wt1b, Wt2b, XWxb, YWyb, b1e, b2e, WoutE);
    pair_kernel<<<dim3(NN, 2), 256, 0, stream>>>(XWxb, YWyb, Wt1b, Wt2b, U, Y,
                                                 b1e, b2e, WoutE, bout, psi_arr, Mp, Sp);
    finalize_kernel<<<1, 512, 0, stream>>>(psi_arr, Mp, Sp, out);
}

// Round 13
// 55.175 us; speedup vs baseline: 1.7270x; 1.0082x over previous
//
#include <hip/hip_runtime.h>
#include <hip/hip_bf16.h>
#include <math.h>

#define NN 512
#define HH 128
#define FF 32
#define RR 8
#define EPSV 0.1f
#define INV_EPS 10.0f
#define LOG2E 1.4426950408889634f
#define LN2 0.6931471805599453f
#define K2E (INV_EPS * LOG2E)   // exp(x*INV_EPS) = exp2(x*K2E)

// minimax-ish (Chebyshev) coeffs for log2(1+u), u in (0,1], err <= ~2e-4, P(0)=0
#define PC1 1.437284f
#define PC2 (-0.672862f)
#define PC3 0.315362f
#define PC4 (-0.0799600f)

typedef unsigned short ushort_t;
typedef __attribute__((ext_vector_type(8))) short bf16x8;
typedef __attribute__((ext_vector_type(4))) float f32x4;
typedef __attribute__((ext_vector_type(4))) unsigned int u32x4;
typedef __attribute__((ext_vector_type(2))) unsigned int u32x2;

// base-2 softplus, 1 transcendental: g(t) = max(t,0) + poly(2^-|t|)
// g(t) = softplus(z)*log2e with t = z*log2e.
__device__ __forceinline__ float g2(float t) {
    const float u = __builtin_amdgcn_exp2f(-fabsf(t));
    const float p = u * (PC1 + u * (PC2 + u * (PC3 + u * PC4)));
    return fmaxf(t, 0.f) + p;
}
__device__ __forceinline__ ushort_t f2b(float f) {  // fp32 -> bf16 RNE
    unsigned u = __float_as_uint(f);
    return (ushort_t)((u + 0x7fffu + ((u >> 16) & 1u)) >> 16);
}
__device__ __forceinline__ float b2f(ushort_t h) {
    return __uint_as_float(((unsigned)h) << 16);
}
__device__ __forceinline__ unsigned pk2(float a, float b) {  // 2x fp32 -> packed bf16x2
    __hip_bfloat162 h = __float22bfloat162_rn(make_float2(a, b));
    return *reinterpret_cast<unsigned*>(&h);
}

// ---- K0 prep: Wt bf16 W^T (unscaled); XWxb=(X@Wx+b0)*log2e, YWyb=(Y@Wy)*log2e (bf16);
//      b1e=b1*log2e, b2e=b2*log2e, WoutE=Wout*ln2 (fp32) ----
__global__ __launch_bounds__(256) void prep_kernel(
    const float* __restrict__ X, const float* __restrict__ Y,
    const float* __restrict__ Wx, const float* __restrict__ Wy,
    const float* __restrict__ b0, const float* __restrict__ W1, const float* __restrict__ W2,
    const float* __restrict__ b1, const float* __restrict__ b2, const float* __restrict__ Wout,
    ushort_t* __restrict__ Wt1b, ushort_t* __restrict__ Wt2b,
    ushort_t* __restrict__ XWxb, ushort_t* __restrict__ YWyb,
    float* __restrict__ b1e, float* __restrict__ b2e, float* __restrict__ WoutE) {
    int gid = blockIdx.x * 256 + threadIdx.x;
    if (gid < 32768) {
        int sel = gid >> 14;
        int idx = gid & 16383;                  // n*128 + k
        int n = idx >> 7, k = idx & 127;
        (sel ? Wt2b : Wt1b)[idx] = f2b((sel ? W2 : W1)[k * HH + n]);
    } else if (gid < 98304) {
        int g = gid - 32768;
        int i = g >> 7, h = g & 127;
        float s = b0[h];
#pragma unroll
        for (int f = 0; f < FF; ++f) s += X[i * FF + f] * Wx[f * HH + h];
        XWxb[g] = f2b(s * LOG2E);
    } else if (gid < 163840) {
        int g = gid - 98304;
        int i = g >> 7, h = g & 127;
        float s = 0.f;
#pragma unroll
        for (int r = 0; r < RR; ++r) s += Y[i * RR + r] * Wy[r * HH + h];
        YWyb[g] = f2b(s * LOG2E);
    } else if (gid < 163968) {
        b1e[gid - 163840] = b1[gid - 163840] * LOG2E;
    } else if (gid < 164096) {
        b2e[gid - 163968] = b2[gid - 163968] * LOG2E;
    } else if (gid < 164224) {
        WoutE[gid - 164096] = Wout[gid - 164096] * LN2;
    }
}

// Flipped layer (R9-proven): acc[mt][nt] = Wt(A) @ Hin(B) + bias; D[m=h_out][n=j].
__device__ __forceinline__ void layer_flip(
    const ushort_t* __restrict__ Hin, const ushort_t* __restrict__ WtG,
    const float* __restrict__ bias, f32x4 acc[2][4], int r16, int g4, int wv) {
    const int hbase = wv * 32 + g4 * 4;
#pragma unroll
    for (int mt = 0; mt < 2; ++mt) {
        float4 bb = *(const float4*)&bias[hbase + mt * 16];
#pragma unroll
        for (int nt = 0; nt < 4; ++nt) {
            acc[mt][nt][0] = bb.x; acc[mt][nt][1] = bb.y;
            acc[mt][nt][2] = bb.z; acc[mt][nt][3] = bb.w;
        }
    }
    bf16x8 afr[2][4];
#pragma unroll
    for (int mt = 0; mt < 2; ++mt)
#pragma unroll
        for (int ks = 0; ks < 4; ++ks)
            afr[mt][ks] = *(const bf16x8*)&WtG[(wv * 32 + mt * 16 + r16) * HH + ks * 32 + g4 * 8];
#pragma unroll
    for (int ks = 0; ks < 4; ++ks) {
        const int kb = ks * 32 + g4 * 8;
#pragma unroll
        for (int nt = 0; nt < 4; ++nt) {
            const int j = nt * 16 + r16;
            bf16x8 bfr = *(const bf16x8*)&Hin[j * HH + (kb ^ ((j & 7) << 3))];
            acc[0][nt] = __builtin_amdgcn_mfma_f32_16x16x32_bf16(afr[0][ks], bfr, acc[0][nt], 0, 0, 0);
            acc[1][nt] = __builtin_amdgcn_mfma_f32_16x16x32_bf16(afr[1][ks], bfr, acc[1][nt], 0, 0, 0);
        }
    }
}

// ---- K1: per (i, j-half): 4 chunks of 64 j; 2 barriers/chunk; LSE fully post-loop ----
__global__ __launch_bounds__(256, 2) void pair_kernel(
    const ushort_t* __restrict__ XWxb, const ushort_t* __restrict__ YWyb,
    const ushort_t* __restrict__ Wt1b, const ushort_t* __restrict__ Wt2b,
    const float* __restrict__ U, const float* __restrict__ Y,
    const float* __restrict__ b1e, const float* __restrict__ b2e,
    const float* __restrict__ WoutE, const float* __restrict__ bout,
    float* __restrict__ psi_arr, float* __restrict__ Mp, float* __restrict__ Sp) {
    __shared__ ushort_t Hs0[64 * HH];   // 16 KB (swizzled bf16, t-domain)
    __shared__ ushort_t Hs1[64 * HH];   // 16 KB
    __shared__ float psum[4][4][64];    // [chunk][wave][j] psi partials, 4 KB

    const int i = blockIdx.x;
    const int half = blockIdx.y;
    const int t = threadIdx.x;
    const int wv = t >> 6;
    const int r16 = t & 15;
    const int g4 = (t >> 4) & 3;
    const int srow = t >> 4;            // 0..15 (staging row group)
    const float boutv = bout[0];

    // per-thread slice of XWx_i (+b0, *log2e), cols r16*8..+7
    float axf[8];
    {
        bf16x8 axv = *(const bf16x8*)&XWxb[i * HH + r16 * 8];
#pragma unroll
        for (int e = 0; e < 8; ++e) axf[e] = b2f((ushort_t)axv[e]);
    }
    // hoisted cost dot: costr[c] = U[i] . Y[j0(c) + (t&63)]
    float costr[4];
    {
        const float4 u0 = *(const float4*)&U[i * RR];
        const float4 u1 = *(const float4*)&U[i * RR + 4];
#pragma unroll
        for (int c = 0; c < 4; ++c) {
            const int j = half * 256 + c * 64 + (t & 63);
            const float4 y0 = *(const float4*)&Y[j * RR];
            const float4 y1 = *(const float4*)&Y[j * RR + 4];
            costr[c] = u0.x * y0.x + u0.y * y0.y + u0.z * y0.z + u0.w * y0.w +
                       u1.x * y1.x + u1.y * y1.y + u1.z * y1.z + u1.w * y1.w;
        }
    }
    // hoisted layer-1 weight fragments + bias (loop-invariant; wave owns h in [wv*32,+32))
    bf16x8 afr1[2][4];
#pragma unroll
    for (int mt = 0; mt < 2; ++mt)
#pragma unroll
        for (int ks = 0; ks < 4; ++ks)
            afr1[mt][ks] = *(const bf16x8*)&Wt1b[(wv * 32 + mt * 16 + r16) * HH + ks * 32 + g4 * 8];
    float4 bias1h[2];
    bias1h[0] = *(const float4*)&b1e[wv * 32 + g4 * 4];
    bias1h[1] = *(const float4*)&b1e[wv * 32 + 16 + g4 * 4];
    // hoisted epilogue weights (loop-invariant)
    float4 woutr[2];
    woutr[0] = *(const float4*)&WoutE[wv * 32 + g4 * 4];
    woutr[1] = *(const float4*)&WoutE[wv * 32 + 16 + g4 * 4];

    f32x4 acc[2][4];
    bf16x8 pf[4];                       // prefetched YWy rows for current chunk

    // prologue: prefetch chunk 0
#pragma unroll
    for (int s = 0; s < 4; ++s)
        pf[s] = *(const bf16x8*)&YWyb[(half * 256 + s * 16 + srow) * HH + r16 * 8];

#pragma unroll
    for (int c = 0; c < 4; ++c) {
        const int j0 = half * 256 + c * 64;
        // ---- stage H0 from prefetched regs: g2(axf + yv), swizzled bf16 ----
#pragma unroll
        for (int s = 0; s < 4; ++s) {
            const int p = s * 16 + srow;
            const bf16x8 yv = pf[s];
            unsigned pk[4];
#pragma unroll
            for (int e = 0; e < 4; ++e) {
                float v0 = g2(axf[2 * e]     + b2f((ushort_t)yv[2 * e]));
                float v1 = g2(axf[2 * e + 1] + b2f((ushort_t)yv[2 * e + 1]));
                pk[e] = pk2(v0, v1);
            }
            *(u32x4*)&Hs0[p * HH + ((r16 ^ (p & 7)) << 3)] = *(u32x4*)pk;
        }
        __syncthreads();                // A: H0 ready (also orders L2(c-1) Hs1-reads)
        // issue next chunk's prefetch now; latency hides under both layers
        if (c < 3) {
#pragma unroll
            for (int s = 0; s < 4; ++s)
                pf[s] = *(const bf16x8*)&YWyb[(j0 + 64 + s * 16 + srow) * HH + r16 * 8];
        }
        // ---- layer 1 (h-owned, hoisted weights): t1 = W1t @ g(t0) + b1e ----
#pragma unroll
        for (int mt = 0; mt < 2; ++mt)
#pragma unroll
            for (int nt = 0; nt < 4; ++nt) {
                acc[mt][nt][0] = bias1h[mt].x; acc[mt][nt][1] = bias1h[mt].y;
                acc[mt][nt][2] = bias1h[mt].z; acc[mt][nt][3] = bias1h[mt].w;
            }
#pragma unroll
        for (int ks = 0; ks < 4; ++ks) {
            const int kb = ks * 32 + g4 * 8;
#pragma unroll
            for (int nt = 0; nt < 4; ++nt) {
                const int j = nt * 16 + r16;
                bf16x8 bfr = *(const bf16x8*)&Hs0[j * HH + (kb ^ ((j & 7) << 3))];
                acc[0][nt] = __builtin_amdgcn_mfma_f32_16x16x32_bf16(afr1[0][ks], bfr, acc[0][nt], 0, 0, 0);
                acc[1][nt] = __builtin_amdgcn_mfma_f32_16x16x32_bf16(afr1[1][ks], bfr, acc[1][nt], 0, 0, 0);
            }
        }
        // store H1[j][h1] = g2(t1) bf16 swizzled (4 consecutive h1 -> b64)
#pragma unroll
        for (int mt = 0; mt < 2; ++mt) {
            const int hb = wv * 32 + mt * 16 + g4 * 4;
#pragma unroll
            for (int nt = 0; nt < 4; ++nt) {
                const int j = nt * 16 + r16;
                u32x2 wv2;
                wv2[0] = pk2(g2(acc[mt][nt][0]), g2(acc[mt][nt][1]));
                wv2[1] = pk2(g2(acc[mt][nt][2]), g2(acc[mt][nt][3]));
                *(u32x2*)&Hs1[j * HH + (hb ^ ((j & 7) << 3))] = wv2;
            }
        }
        __syncthreads();                // X: H1 ready (also orders Hs0-reads vs stage(c+1))
        // ---- layer 2 (h-owned, batch loads): t2 = W2t @ g(t1) + b2e ----
        layer_flip(Hs1, Wt2b, b2e, acc, r16, g4, wv);
        // ---- epilogue in-register: psi partial -> chunk slab psum[c] ----
        {
            float part[4] = {0.f, 0.f, 0.f, 0.f};
#pragma unroll
            for (int mt = 0; mt < 2; ++mt) {
                const float wr[4] = {woutr[mt].x, woutr[mt].y, woutr[mt].z, woutr[mt].w};
#pragma unroll
                for (int r = 0; r < 4; ++r) {
                    const float wgt = wr[r];
#pragma unroll
                    for (int nt = 0; nt < 4; ++nt)
                        part[nt] += g2(acc[mt][nt][r]) * wgt;
                }
            }
#pragma unroll
            for (int nt = 0; nt < 4; ++nt) {
                part[nt] += __shfl_xor(part[nt], 16);
                part[nt] += __shfl_xor(part[nt], 32);
            }
            if (g4 == 0) {
#pragma unroll
                for (int nt = 0; nt < 4; ++nt) psum[c][wv][nt * 16 + r16] = part[nt];
            }
        }
        // no barrier here: psum[c] slab is read only after the final barrier
    }
    __syncthreads();                    // F: all psum slabs ready
    // ---- post-loop online LSE over 4 chunks (t<64 lanes, one j-column each) ----
    if (t < 64) {
        float m_l = -INFINITY, s_l = 0.f;
#pragma unroll
        for (int c = 0; c < 4; ++c) {
            const float psi = boutv + psum[c][0][t] + psum[c][1][t] +
                              psum[c][2][t] + psum[c][3][t];
            const int j = half * 256 + c * 64 + t;
            if (j == i) psi_arr[i] = psi;
            const float sv = costr[c] - psi;
            const float mn = fmaxf(m_l, sv);
            s_l = s_l * __builtin_amdgcn_exp2f((m_l - mn) * K2E) +
                  __builtin_amdgcn_exp2f((sv - mn) * K2E);
            m_l = mn;
        }
        float M = m_l;
#pragma unroll
        for (int o = 1; o < 64; o <<= 1) M = fmaxf(M, __shfl_xor(M, o));
        float S = s_l * __builtin_amdgcn_exp2f((m_l - M) * K2E);
#pragma unroll
        for (int o = 1; o < 64; o <<= 1) S += __shfl_xor(S, o);
        if (t == 0) {
            Mp[i * 2 + half] = M;
            Sp[i * 2 + half] = S;
        }
    }
}

// ---- K2: combine per-half partials -> phi_i; total = mean(phi) + mean(psi) ----
__global__ __launch_bounds__(512) void finalize_kernel(
    const float* __restrict__ psi_arr, const float* __restrict__ Mp,
    const float* __restrict__ Sp, float* __restrict__ out) {
    __shared__ float red[8];
    const int t = threadIdx.x;  // = i
    const float M0 = Mp[2 * t], M1 = Mp[2 * t + 1];
    const float S0 = Sp[2 * t], S1 = Sp[2 * t + 1];
    const float Mg = fmaxf(M0, M1);
    const float S = S0 * __expf((M0 - Mg) * INV_EPS) + S1 * __expf((M1 - Mg) * INV_EPS);
    const float phi = EPSV * (__logf(S) - __logf((float)NN)) + Mg;
    float v = phi + psi_arr[t];
#pragma unroll
    for (int o = 1; o < 64; o <<= 1) v += __shfl_xor(v, o);
    if ((t & 63) == 0) red[t >> 6] = v;
    __syncthreads();
    if (t == 0) {
        float tot = 0.f;
#pragma unroll
        for (int w = 0; w < 8; ++w) tot += red[w];
        out[0] = tot / (float)NN;
    }
}

extern "C" void kernel_launch(void* const* d_in, const int* in_sizes, int n_in,
                              void* d_out, int out_size, void* d_ws, size_t ws_size,
                              hipStream_t stream) {
    (void)in_sizes; (void)n_in; (void)out_size; (void)ws_size;
    const float* X    = (const float*)d_in[0];
    const float* U    = (const float*)d_in[1];
    const float* Y    = (const float*)d_in[2];
    const float* Wx   = (const float*)d_in[3];
    const float* Wy   = (const float*)d_in[4];
    const float* b0   = (const float*)d_in[5];
    const float* W1   = (const float*)d_in[6];
    const float* b1   = (const float*)d_in[7];
    const float* W2   = (const float*)d_in[8];
    const float* b2   = (const float*)d_in[9];
    const float* Wout = (const float*)d_in[10];
    const float* bout = (const float*)d_in[11];
    float* out = (float*)d_out;

    char* ws = (char*)d_ws;
    ushort_t* Wt1b    = (ushort_t*)(ws);                   // 32 KB
    ushort_t* Wt2b    = (ushort_t*)(ws + 32768);           // 32 KB
    ushort_t* XWxb    = (ushort_t*)(ws + 65536);           // 128 KB
    ushort_t* YWyb    = (ushort_t*)(ws + 196608);          // 128 KB
    float*    psi_arr = (float*)(ws + 327680);             // 2 KB
    float*    Mp      = (float*)(ws + 329728);             // 4 KB
    float*    Sp      = (float*)(ws + 333824);             // 4 KB
    float*    b1e     = (float*)(ws + 337920);             // 512 B
    float*    b2e     = (float*)(ws + 338432);             // 512 B
    float*    WoutE   = (float*)(ws + 338944);             // 512 B

    prep_kernel<<<642, 256, 0, stream>>>(X, Y, Wx, Wy, b0, W1, W2, b1, b2, Wout,
                                         Wt1b, Wt2b, XWxb, YWyb, b1e, b2e, WoutE);
    pair_kernel<<<dim3(NN, 2), 256, 0, stream>>>(XWxb, YWyb, Wt1b, Wt2b, U, Y,
                                                 b1e, b2e, WoutE, bout, psi_arr, Mp, Sp);
    finalize_kernel<<<1, 512, 0, stream>>>(psi_arr, Mp, Sp, out);
}

// Round 14
// 53.439 us; speedup vs baseline: 1.7832x; 1.0325x over previous
//
#include <hip/hip_runtime.h>
#include <hip/hip_bf16.h>
#include <math.h>

#define NN 512
#define HH 128
#define FF 32
#define RR 8
#define EPSV 0.1f
#define INV_EPS 10.0f
#define LOG2E 1.4426950408889634f
#define LN2 0.6931471805599453f
#define K2E (INV_EPS * LOG2E)   // exp(x*INV_EPS) = exp2(x*K2E)

// minimax-ish coeffs for log2(1+u), u in (0,1], err <= ~2e-4, P(0)=0
#define PC1 1.437284f
#define PC2 (-0.672862f)
#define PC3 0.315362f
#define PC4 (-0.0799600f)

typedef unsigned short ushort_t;
typedef __attribute__((ext_vector_type(8))) short bf16x8;
typedef __attribute__((ext_vector_type(4))) float f32x4;
typedef __attribute__((ext_vector_type(4))) unsigned int u32x4;
typedef __attribute__((ext_vector_type(2))) unsigned int u32x2;

// base-2 softplus, 1 transcendental: g(t) = max(t,0) + poly(2^-|t|)
__device__ __forceinline__ float g2(float t) {
    const float u = __builtin_amdgcn_exp2f(-fabsf(t));
    const float p = u * (PC1 + u * (PC2 + u * (PC3 + u * PC4)));
    return fmaxf(t, 0.f) + p;
}
__device__ __forceinline__ ushort_t f2b(float f) {  // fp32 -> bf16 RNE
    unsigned u = __float_as_uint(f);
    return (ushort_t)((u + 0x7fffu + ((u >> 16) & 1u)) >> 16);
}
__device__ __forceinline__ float b2f(ushort_t h) {
    return __uint_as_float(((unsigned)h) << 16);
}
__device__ __forceinline__ unsigned pk2(float a, float b) {  // 2x fp32 -> packed bf16x2
    __hip_bfloat162 h = __float22bfloat162_rn(make_float2(a, b));
    return *reinterpret_cast<unsigned*>(&h);
}

// ---- K0 prep: Wt bf16 W^T (unscaled); XWxb=(X@Wx+b0)*log2e, YWyb=(Y@Wy)*log2e (bf16);
//      b1e=b1*log2e, b2e=b2*log2e, WoutE=Wout*ln2 (fp32) ----
__global__ __launch_bounds__(256) void prep_kernel(
    const float* __restrict__ X, const float* __restrict__ Y,
    const float* __restrict__ Wx, const float* __restrict__ Wy,
    const float* __restrict__ b0, const float* __restrict__ W1, const float* __restrict__ W2,
    const float* __restrict__ b1, const float* __restrict__ b2, const float* __restrict__ Wout,
    ushort_t* __restrict__ Wt1b, ushort_t* __restrict__ Wt2b,
    ushort_t* __restrict__ XWxb, ushort_t* __restrict__ YWyb,
    float* __restrict__ b1e, float* __restrict__ b2e, float* __restrict__ WoutE) {
    int gid = blockIdx.x * 256 + threadIdx.x;
    if (gid < 32768) {
        int sel = gid >> 14;
        int idx = gid & 16383;                  // n*128 + k
        int n = idx >> 7, k = idx & 127;
        (sel ? Wt2b : Wt1b)[idx] = f2b((sel ? W2 : W1)[k * HH + n]);
    } else if (gid < 98304) {
        int g = gid - 32768;
        int i = g >> 7, h = g & 127;
        float s = b0[h];
#pragma unroll
        for (int f = 0; f < FF; ++f) s += X[i * FF + f] * Wx[f * HH + h];
        XWxb[g] = f2b(s * LOG2E);
    } else if (gid < 163840) {
        int g = gid - 98304;
        int i = g >> 7, h = g & 127;
        float s = 0.f;
#pragma unroll
        for (int r = 0; r < RR; ++r) s += Y[i * RR + r] * Wy[r * HH + h];
        YWyb[g] = f2b(s * LOG2E);
    } else if (gid < 163968) {
        b1e[gid - 163840] = b1[gid - 163840] * LOG2E;
    } else if (gid < 164096) {
        b2e[gid - 163968] = b2[gid - 163968] * LOG2E;
    } else if (gid < 164224) {
        WoutE[gid - 164096] = Wout[gid - 164096] * LN2;
    }
}

// Flipped layer (R9-proven): acc[mt][nt] = Wt(A) @ Hin(B) + bias; D[m=h_out][n=j].
__device__ __forceinline__ void layer_flip(
    const ushort_t* __restrict__ Hin, const ushort_t* __restrict__ WtG,
    const float* __restrict__ bias, f32x4 acc[2][4], int r16, int g4, int wv) {
    const int hbase = wv * 32 + g4 * 4;
#pragma unroll
    for (int mt = 0; mt < 2; ++mt) {
        float4 bb = *(const float4*)&bias[hbase + mt * 16];
#pragma unroll
        for (int nt = 0; nt < 4; ++nt) {
            acc[mt][nt][0] = bb.x; acc[mt][nt][1] = bb.y;
            acc[mt][nt][2] = bb.z; acc[mt][nt][3] = bb.w;
        }
    }
    bf16x8 afr[2][4];
#pragma unroll
    for (int mt = 0; mt < 2; ++mt)
#pragma unroll
        for (int ks = 0; ks < 4; ++ks)
            afr[mt][ks] = *(const bf16x8*)&WtG[(wv * 32 + mt * 16 + r16) * HH + ks * 32 + g4 * 8];
#pragma unroll
    for (int ks = 0; ks < 4; ++ks) {
        const int kb = ks * 32 + g4 * 8;
#pragma unroll
        for (int nt = 0; nt < 4; ++nt) {
            const int j = nt * 16 + r16;
            bf16x8 bfr = *(const bf16x8*)&Hin[j * HH + (kb ^ ((j & 7) << 3))];
            acc[0][nt] = __builtin_amdgcn_mfma_f32_16x16x32_bf16(afr[0][ks], bfr, acc[0][nt], 0, 0, 0);
            acc[1][nt] = __builtin_amdgcn_mfma_f32_16x16x32_bf16(afr[1][ks], bfr, acc[1][nt], 0, 0, 0);
        }
    }
}

// ---- K1: one block per (i, 64-j chunk); 4096 independent blocks; 3 barriers total ----
__global__ __launch_bounds__(256, 2) void pair_kernel(
    const ushort_t* __restrict__ XWxb, const ushort_t* __restrict__ YWyb,
    const ushort_t* __restrict__ Wt1b, const ushort_t* __restrict__ Wt2b,
    const float* __restrict__ U, const float* __restrict__ Y,
    const float* __restrict__ b1e, const float* __restrict__ b2e,
    const float* __restrict__ WoutE, const float* __restrict__ bout,
    float* __restrict__ psi_arr, float* __restrict__ Mp, float* __restrict__ Sp) {
    __shared__ ushort_t Hs0[64 * HH];   // 16 KB (swizzled bf16, t-domain)
    __shared__ ushort_t Hs1[64 * HH];   // 16 KB
    __shared__ float psum[4][64];       // [wave][j] psi partials, 1 KB

    const int i = blockIdx.x;
    const int q = blockIdx.y;           // j-chunk index 0..7
    const int j0 = q * 64;
    const int t = threadIdx.x;
    const int wv = t >> 6;
    const int r16 = t & 15;
    const int g4 = (t >> 4) & 3;
    const int srow = t >> 4;            // 0..15 (staging row group)
    const float boutv = bout[0];

    // per-thread slice of XWx_i (+b0, *log2e), cols r16*8..+7
    float axf[8];
    {
        bf16x8 axv = *(const bf16x8*)&XWxb[i * HH + r16 * 8];
#pragma unroll
        for (int e = 0; e < 8; ++e) axf[e] = b2f((ushort_t)axv[e]);
    }
    // cost dot for this lane's j (used by t<64 in LSE phase)
    float cost;
    {
        const int j = j0 + (t & 63);
        const float4 u0 = *(const float4*)&U[i * RR];
        const float4 u1 = *(const float4*)&U[i * RR + 4];
        const float4 y0 = *(const float4*)&Y[j * RR];
        const float4 y1 = *(const float4*)&Y[j * RR + 4];
        cost = u0.x * y0.x + u0.y * y0.y + u0.z * y0.z + u0.w * y0.w +
               u1.x * y1.x + u1.y * y1.y + u1.z * y1.z + u1.w * y1.w;
    }
    // hoisted layer-1 weight fragments + bias (wave owns h in [wv*32,+32))
    bf16x8 afr1[2][4];
#pragma unroll
    for (int mt = 0; mt < 2; ++mt)
#pragma unroll
        for (int ks = 0; ks < 4; ++ks)
            afr1[mt][ks] = *(const bf16x8*)&Wt1b[(wv * 32 + mt * 16 + r16) * HH + ks * 32 + g4 * 8];
    float4 bias1h[2];
    bias1h[0] = *(const float4*)&b1e[wv * 32 + g4 * 4];
    bias1h[1] = *(const float4*)&b1e[wv * 32 + 16 + g4 * 4];
    float4 woutr[2];
    woutr[0] = *(const float4*)&WoutE[wv * 32 + g4 * 4];
    woutr[1] = *(const float4*)&WoutE[wv * 32 + 16 + g4 * 4];

    // ---- stage H0 = g2(axf + YWy[j]) bf16, XOR-swizzled ----
#pragma unroll
    for (int s = 0; s < 4; ++s) {
        const int p = s * 16 + srow;
        bf16x8 yv = *(const bf16x8*)&YWyb[(j0 + p) * HH + r16 * 8];
        unsigned pk[4];
#pragma unroll
        for (int e = 0; e < 4; ++e) {
            float v0 = g2(axf[2 * e]     + b2f((ushort_t)yv[2 * e]));
            float v1 = g2(axf[2 * e + 1] + b2f((ushort_t)yv[2 * e + 1]));
            pk[e] = pk2(v0, v1);
        }
        *(u32x4*)&Hs0[p * HH + ((r16 ^ (p & 7)) << 3)] = *(u32x4*)pk;
    }
    __syncthreads();                    // A: H0 ready

    // ---- layer 1 (h-owned, hoisted weights): t1 = W1t @ g(t0) + b1e ----
    f32x4 acc[2][4];
#pragma unroll
    for (int mt = 0; mt < 2; ++mt)
#pragma unroll
        for (int nt = 0; nt < 4; ++nt) {
            acc[mt][nt][0] = bias1h[mt].x; acc[mt][nt][1] = bias1h[mt].y;
            acc[mt][nt][2] = bias1h[mt].z; acc[mt][nt][3] = bias1h[mt].w;
        }
#pragma unroll
    for (int ks = 0; ks < 4; ++ks) {
        const int kb = ks * 32 + g4 * 8;
#pragma unroll
        for (int nt = 0; nt < 4; ++nt) {
            const int j = nt * 16 + r16;
            bf16x8 bfr = *(const bf16x8*)&Hs0[j * HH + (kb ^ ((j & 7) << 3))];
            acc[0][nt] = __builtin_amdgcn_mfma_f32_16x16x32_bf16(afr1[0][ks], bfr, acc[0][nt], 0, 0, 0);
            acc[1][nt] = __builtin_amdgcn_mfma_f32_16x16x32_bf16(afr1[1][ks], bfr, acc[1][nt], 0, 0, 0);
        }
    }
    // store H1[j][h1] = g2(t1) bf16 swizzled (4 consecutive h1 -> b64)
#pragma unroll
    for (int mt = 0; mt < 2; ++mt) {
        const int hb = wv * 32 + mt * 16 + g4 * 4;
#pragma unroll
        for (int nt = 0; nt < 4; ++nt) {
            const int j = nt * 16 + r16;
            u32x2 wv2;
            wv2[0] = pk2(g2(acc[mt][nt][0]), g2(acc[mt][nt][1]));
            wv2[1] = pk2(g2(acc[mt][nt][2]), g2(acc[mt][nt][3]));
            *(u32x2*)&Hs1[j * HH + (hb ^ ((j & 7) << 3))] = wv2;
        }
    }
    __syncthreads();                    // X: H1 ready

    // ---- layer 2 (h-owned, batch loads): t2 = W2t @ g(t1) + b2e ----
    layer_flip(Hs1, Wt2b, b2e, acc, r16, g4, wv);
    // ---- epilogue in-register: psi partial -> psum ----
    {
        float part[4] = {0.f, 0.f, 0.f, 0.f};
#pragma unroll
        for (int mt = 0; mt < 2; ++mt) {
            const float wr[4] = {woutr[mt].x, woutr[mt].y, woutr[mt].z, woutr[mt].w};
#pragma unroll
            for (int r = 0; r < 4; ++r) {
                const float wgt = wr[r];
#pragma unroll
                for (int nt = 0; nt < 4; ++nt)
                    part[nt] += g2(acc[mt][nt][r]) * wgt;
            }
        }
#pragma unroll
        for (int nt = 0; nt < 4; ++nt) {
            part[nt] += __shfl_xor(part[nt], 16);
            part[nt] += __shfl_xor(part[nt], 32);
        }
        if (g4 == 0) {
#pragma unroll
            for (int nt = 0; nt < 4; ++nt) psum[wv][nt * 16 + r16] = part[nt];
        }
    }
    __syncthreads();                    // F: psum ready

    // ---- single-chunk LSE partial (t<64 lanes, one j each) ----
    if (t < 64) {
        const float psi = boutv + psum[0][t] + psum[1][t] + psum[2][t] + psum[3][t];
        const int j = j0 + t;
        if (j == i) psi_arr[i] = psi;
        const float sv = cost - psi;
        float M = sv;
#pragma unroll
        for (int o = 1; o < 64; o <<= 1) M = fmaxf(M, __shfl_xor(M, o));
        float S = __builtin_amdgcn_exp2f((sv - M) * K2E);
#pragma unroll
        for (int o = 1; o < 64; o <<= 1) S += __shfl_xor(S, o);
        if (t == 0) {
            Mp[i * 8 + q] = M;
            Sp[i * 8 + q] = S;
        }
    }
}

// ---- K2: combine 8 partials per i -> phi_i; total = mean(phi) + mean(psi) ----
__global__ __launch_bounds__(512) void finalize_kernel(
    const float* __restrict__ psi_arr, const float* __restrict__ Mp,
    const float* __restrict__ Sp, float* __restrict__ out) {
    __shared__ float red[8];
    const int t = threadIdx.x;  // = i
    float Mq[8], Sq[8];
#pragma unroll
    for (int q = 0; q < 8; ++q) { Mq[q] = Mp[t * 8 + q]; Sq[q] = Sp[t * 8 + q]; }
    float Mg = Mq[0];
#pragma unroll
    for (int q = 1; q < 8; ++q) Mg = fmaxf(Mg, Mq[q]);
    float S = 0.f;
#pragma unroll
    for (int q = 0; q < 8; ++q) S += Sq[q] * __builtin_amdgcn_exp2f((Mq[q] - Mg) * K2E);
    const float phi = EPSV * (__logf(S) - __logf((float)NN)) + Mg;
    float v = phi + psi_arr[t];
#pragma unroll
    for (int o = 1; o < 64; o <<= 1) v += __shfl_xor(v, o);
    if ((t & 63) == 0) red[t >> 6] = v;
    __syncthreads();
    if (t == 0) {
        float tot = 0.f;
#pragma unroll
        for (int w = 0; w < 8; ++w) tot += red[w];
        out[0] = tot / (float)NN;
    }
}

extern "C" void kernel_launch(void* const* d_in, const int* in_sizes, int n_in,
                              void* d_out, int out_size, void* d_ws, size_t ws_size,
                              hipStream_t stream) {
    (void)in_sizes; (void)n_in; (void)out_size; (void)ws_size;
    const float* X    = (const float*)d_in[0];
    const float* U    = (const float*)d_in[1];
    const float* Y    = (const float*)d_in[2];
    const float* Wx   = (const float*)d_in[3];
    const float* Wy   = (const float*)d_in[4];
    const float* b0   = (const float*)d_in[5];
    const float* W1   = (const float*)d_in[6];
    const float* b1   = (const float*)d_in[7];
    const float* W2   = (const float*)d_in[8];
    const float* b2   = (const float*)d_in[9];
    const float* Wout = (const float*)d_in[10];
    const float* bout = (const float*)d_in[11];
    float* out = (float*)d_out;

    char* ws = (char*)d_ws;
    ushort_t* Wt1b    = (ushort_t*)(ws);                   // 32 KB
    ushort_t* Wt2b    = (ushort_t*)(ws + 32768);           // 32 KB
    ushort_t* XWxb    = (ushort_t*)(ws + 65536);           // 128 KB
    ushort_t* YWyb    = (ushort_t*)(ws + 196608);          // 128 KB
    float*    psi_arr = (float*)(ws + 327680);             // 2 KB
    float*    Mp      = (float*)(ws + 329728);             // 16 KB
    float*    Sp      = (float*)(ws + 346112);             // 16 KB
    float*    b1e     = (float*)(ws + 362496);             // 512 B
    float*    b2e     = (float*)(ws + 363008);             // 512 B
    float*    WoutE   = (float*)(ws + 363520);             // 512 B

    prep_kernel<<<642, 256, 0, stream>>>(X, Y, Wx, Wy, b0, W1, W2, b1, b2, Wout,
                                         Wt1b, Wt2b, XWxb, YWyb, b1e, b2e, WoutE);
    pair_kernel<<<dim3(NN, 8), 256, 0, stream>>>(XWxb, YWyb, Wt1b, Wt2b, U, Y,
                                                 b1e, b2e, WoutE, bout, psi_arr, Mp, Sp);
    finalize_kernel<<<1, 512, 0, stream>>>(psi_arr, Mp, Sp, out);
}